// Round 8
// baseline (558.057 us; speedup 1.0000x reference)
//
#include <hip/hip_runtime.h>
#include <cstdint>
#include <cstddef>

#define KKSLOTS 25

typedef __attribute__((ext_vector_type(8))) short short8;
typedef __attribute__((ext_vector_type(4))) float f32x4;
typedef __attribute__((ext_vector_type(4))) unsigned short us4;

__device__ __forceinline__ unsigned short f2bf(float f) {
    unsigned u = __float_as_uint(f);
    u += 0x7FFF + ((u >> 16) & 1);           // RNE
    return (unsigned short)(u >> 16);
}
__device__ __forceinline__ float bf2f(unsigned short b) {
    return __uint_as_float((unsigned)b << 16);
}

// ===========================================================================
// CSR build: counting sort of edges by dst, with precomputed spline records.
// Record (int4): {src, packed_slots(4x5bit), bits(f0), bits(f1)}
// ===========================================================================
__global__ void csr_count_kernel(const int* __restrict__ dst, int* __restrict__ cnt, int E) {
    int e = blockIdx.x * blockDim.x + threadIdx.x;
    if (e < E) atomicAdd(&cnt[dst[e]], 1);
}

#define SCAN_B 256
__global__ __launch_bounds__(SCAN_B) void scan1_kernel(const int* __restrict__ cnt,
                                                       int* __restrict__ off,
                                                       int* __restrict__ bsum, int N) {
    __shared__ int tmp[SCAN_B];
    int g = blockIdx.x * SCAN_B + threadIdx.x;
    int v = (g < N) ? cnt[g] : 0;
    tmp[threadIdx.x] = v;
    __syncthreads();
    for (int d = 1; d < SCAN_B; d <<= 1) {
        int t = (threadIdx.x >= d) ? tmp[threadIdx.x - d] : 0;
        __syncthreads();
        tmp[threadIdx.x] += t;
        __syncthreads();
    }
    if (g < N) off[g] = tmp[threadIdx.x] - v;      // exclusive
    if (threadIdx.x == SCAN_B - 1) bsum[blockIdx.x] = tmp[threadIdx.x];
}

__global__ __launch_bounds__(SCAN_B) void scan2_kernel(int* __restrict__ bsum, int nb) {
    __shared__ int tmp[SCAN_B];
    int v = (threadIdx.x < nb) ? bsum[threadIdx.x] : 0;
    tmp[threadIdx.x] = v;
    __syncthreads();
    for (int d = 1; d < SCAN_B; d <<= 1) {
        int t = (threadIdx.x >= d) ? tmp[threadIdx.x - d] : 0;
        __syncthreads();
        tmp[threadIdx.x] += t;
        __syncthreads();
    }
    if (threadIdx.x < nb) bsum[threadIdx.x] = tmp[threadIdx.x] - v;  // exclusive
}

__global__ void scan3_kernel(int* __restrict__ off, const int* __restrict__ bsum, int N) {
    int g = blockIdx.x * SCAN_B + threadIdx.x;
    if (g < N) off[g] += bsum[blockIdx.x];
}

// After this kernel: off[n] == end(n); start(n) = (n==0) ? 0 : off[n-1].
__global__ void csr_fill_kernel(const int* __restrict__ src, const int* __restrict__ dst,
                                const float* __restrict__ pseudo,
                                int* __restrict__ off, int4* __restrict__ rec, int E) {
    int e = blockIdx.x * blockDim.x + threadIdx.x;
    if (e >= E) return;
    int d = dst[e];
    int p = atomicAdd(&off[d], 1);
    float v0 = pseudo[2 * e + 0] * 4.0f;
    float v1 = pseudo[2 * e + 1] * 4.0f;
    float fl0 = floorf(v0), fl1 = floorf(v1);
    float f0 = v0 - fl0, f1 = v1 - fl1;
    int b0 = (int)fl0, b1 = (int)fl1;
    int i0a = min(max(b0, 0), 4),     i1a = min(max(b1, 0), 4);
    int i0b = min(max(b0 + 1, 0), 4), i1b = min(max(b1 + 1, 0), 4);
    // corner order: c = (sel0<<1)|sel1 with sel0 -> f0-side, sel1 -> f1-side
    int s00 = i0a * 5 + i1a;   // (1-f0)(1-f1)
    int s01 = i0a * 5 + i1b;   // (1-f0)f1
    int s10 = i0b * 5 + i1a;   // f0(1-f1)
    int s11 = i0b * 5 + i1b;   // f0 f1
    int packed = s00 | (s01 << 5) | (s10 << 10) | (s11 << 15);
    int4 r;
    r.x = src[e];
    r.y = packed;
    r.z = __float_as_int(f0);
    r.w = __float_as_int(f1);
    rec[p] = r;
}

// ===========================================================================
// fp32 -> bf16 elementwise
// ===========================================================================
__global__ void to_bf16_kernel(const float* __restrict__ in, unsigned short* __restrict__ out, int n) {
    int i = blockIdx.x * 256 + threadIdx.x;
    if (i < n) out[i] = f2bf(in[i]);
}

// ===========================================================================
// build WT[OP][KP] bf16 = transpose of [W ; root] padded with zeros.
// ===========================================================================
template<int KP, int I, int O, int OP>
__global__ void build_wt_kernel(const float* __restrict__ W, const float* __restrict__ root,
                                unsigned short* __restrict__ WT) {
    int idx = blockIdx.x * 256 + threadIdx.x;
    if (idx >= OP * KP) return;
    int o = idx / KP, k = idx - o * KP;
    float v = 0.0f;
    if (o < O) {
        if (k < KKSLOTS * I) v = W[(size_t)k * O + o];
        else if (k < (KKSLOTS + 1) * I) v = root[(size_t)(k - KKSLOTS * I) * O + o];
    }
    WT[idx] = f2bf(v);
}

// ===========================================================================
// segmented accumulation over dst-sorted edges, NODE-ALIGNED wave ranges.
// CORNER-PARALLEL lanes: an edge's 4 spline slots are provably distinct
// (pseudo in [0,1) => i0a != i0b, i1a != i1b), so lane groups handle the 4
// corners of ONE edge concurrently with no LDS races. I<64 additionally runs
// two edges per wave using a second wave-private tile (merged at flush).
// ===========================================================================
template<int I>
__device__ __forceinline__ void edge_proc(float* lat, int chb, int sh, bool selA, bool selB,
                                          int4 r, const unsigned short* __restrict__ xb,
                                          float scale) {
    float f0 = __int_as_float(r.z), f1 = __int_as_float(r.w);
    float w = (selA ? f0 : 1.0f - f0) * (selB ? f1 : 1.0f - f1) * scale;
    int slot = (r.y >> sh) & 31;
    if constexpr (I == 8) {
        float xv = bf2f(xb[(size_t)r.x * 8 + chb]);
        lat[slot * 8 + chb] += w * xv;
    } else {
        us4 xr = *(const us4*)&xb[(size_t)r.x * I + chb];
        float* d = lat + slot * I + chb;
        f32x4 v = *(f32x4*)d;
        v[0] += w * bf2f(xr[0]);
        v[1] += w * bf2f(xr[1]);
        v[2] += w * bf2f(xr[2]);
        v[3] += w * bf2f(xr[3]);
        *(f32x4*)d = v;
    }
}

template<int I, int KP>
__global__ __launch_bounds__(256) void seg_accum_kernel(
        const unsigned short* __restrict__ xb, const int4* __restrict__ rec,
        const int* __restrict__ off, unsigned short* __restrict__ accB,
        int nlo, int nhi) {
    constexpr int SLOTS = KKSLOTS * I;
    constexpr bool DUAL = (I != 64);
    constexpr int TILE = DUAL ? 2 * SLOTS : SLOTS;
    __shared__ __align__(16) float la_all[4][TILE];
    int wline = threadIdx.x >> 6, lane = threadIdx.x & 63;
    float* la = la_all[wline];
    int wid = blockIdx.x * 4 + wline;
    int nwt = gridDim.x << 2;

    int e_lo = (nlo == 0) ? 0 : off[nlo - 1];
    int e_hi = off[nhi - 1];
    long long span = (long long)e_hi - e_lo;
    int t0 = e_lo + (int)(span * wid / nwt);
    int t1 = e_lo + (int)(span * (wid + 1) / nwt);

    int ns, ne;
    {   int lo = nlo, hi = nhi;
        while (lo < hi) { int m = (lo + hi) >> 1; if (off[m] > t0) hi = m; else lo = m + 1; }
        ns = (wid == 0) ? nlo : lo; }
    {   int lo = nlo, hi = nhi;
        while (lo < hi) { int m = (lo + hi) >> 1; if (off[m] > t1) hi = m; else lo = m + 1; }
        ne = (wid == nwt - 1) ? nhi : lo; }
    if (ns >= ne) return;

    // per-lane invariants
    int corner, chb;
    float* lat;
    if constexpr (I == 64)      { corner = lane >> 4;        chb = (lane & 15) * 4; lat = la; }
    else if constexpr (I == 32) { corner = (lane >> 3) & 3;  chb = (lane & 7) * 4;  lat = la + (lane >> 5) * SLOTS; }
    else                        { corner = (lane >> 3) & 3;  chb = lane & 7;        lat = la + (lane >> 5) * SLOTS; }
    int sh = corner * 5;
    bool selA = (corner & 2) != 0, selB = (corner & 1) != 0;
    int h = lane >> 5;

    for (int t = lane; t < TILE; t += 64) la[t] = 0.0f;

    int j = (ns == 0) ? 0 : off[ns - 1];
    for (int n = ns; n < ne; ++n) {
        int je = off[n];
        int jstart = j;
        if constexpr (!DUAL) {
            while (j + 2 <= je) {
                int4 r0 = rec[j], r1 = rec[j + 1];
                edge_proc<I>(lat, chb, sh, selA, selB, r0, xb, 1.0f);
                edge_proc<I>(lat, chb, sh, selA, selB, r1, xb, 1.0f);
                j += 2;
            }
            if (j < je) { edge_proc<I>(lat, chb, sh, selA, selB, rec[j], xb, 1.0f); ++j; }
        } else {
            while (j < je) {
                int idx = j + h;
                int cl = min(idx, je - 1);
                int4 r = rec[cl];
                float scale = (idx < je) ? 1.0f : 0.0f;
                edge_proc<I>(lat, chb, sh, selA, selB, r, xb, scale);
                j += 2;
            }
            j = je;
        }

        // flush node n: row = [bf16(acc * 1/deg) | hin | zeros], packed b32 stores
        float dinv = 1.0f / fmaxf((float)(je - jstart), 1.0f);
        unsigned* drow = (unsigned*)(accB + (size_t)(n - nlo) * KP);
        const unsigned* hrow = (const unsigned*)(xb + (size_t)n * I);
        for (int t = lane; t < KP / 2; t += 64) {
            int e0 = 2 * t;
            if (e0 < SLOTS) {
                float v0 = la[e0], v1 = la[e0 + 1];
                if constexpr (DUAL) { v0 += la[SLOTS + e0]; v1 += la[SLOTS + e0 + 1]; }
                v0 *= dinv; v1 *= dinv;
                drow[t] = (unsigned)f2bf(v0) | ((unsigned)f2bf(v1) << 16);
            } else {
                int ii = e0 - SLOTS;
                drow[t] = (ii < I) ? hrow[ii >> 1] : 0u;
            }
        }
        for (int t = lane; t < TILE; t += 64) la[t] = 0.0f;
    }
}

// ===========================================================================
// MFMA contraction: hout[n][o] = ELU( accB[n][:] . WT[o][:] + bias[o] )
// ===========================================================================
template<int KP, int O, int OP>
__global__ __launch_bounds__(256) void contract_mfma_kernel(
        const unsigned short* __restrict__ accB, const unsigned short* __restrict__ WT,
        const float* __restrict__ bias, unsigned short* __restrict__ hout,
        int nlo, int nhi) {
    constexpr int NF = OP / 16;
    constexpr int LDW = 40;                    // padded LDS row stride (bf16 units)
    __shared__ unsigned short wTl[OP][LDW];
    int tid = threadIdx.x;
    int wv = tid >> 6, lane = tid & 63;
    int quad = lane >> 4, l16 = lane & 15;
    int n0 = nlo + blockIdx.x * 64;

    int an = n0 + wv * 16 + l16;               // node for A-operand
    int arow = min(an, nhi - 1) - nlo;

    f32x4 acc[NF];
    #pragma unroll
    for (int t = 0; t < NF; ++t) acc[t] = (f32x4){0.0f, 0.0f, 0.0f, 0.0f};

    for (int k0 = 0; k0 < KP; k0 += 32) {
        for (int t = tid; t < OP * 8; t += 256) {
            int o = t >> 3;
            int kk = (t & 7) * 4;
            *(us4*)&wTl[o][kk] = *(const us4*)&WT[(size_t)o * KP + k0 + kk];
        }
        __syncthreads();
        short8 a = *(const short8*)(accB + (size_t)arow * KP + k0 + quad * 8);
        #pragma unroll
        for (int t = 0; t < NF; ++t) {
            short8 b = *(const short8*)&wTl[t * 16 + l16][quad * 8];
            acc[t] = __builtin_amdgcn_mfma_f32_16x16x32_bf16(a, b, acc[t], 0, 0, 0);
        }
        __syncthreads();
    }

    #pragma unroll
    for (int t = 0; t < NF; ++t) {
        int o = t * 16 + l16;
        if (o >= O) continue;
        float bs = bias[o];
        #pragma unroll
        for (int r = 0; r < 4; ++r) {
            int n = n0 + wv * 16 + quad * 4 + r;
            if (n >= nhi) continue;
            float v = acc[t][r] + bs;
            v = (v > 0.0f) ? v : expm1f(v);
            hout[(size_t)n * O + o] = f2bf(v);
        }
    }
}

// ===========================================================================
// segmented graph sum (batch sorted, h3 bf16) + fused count + head
// ===========================================================================
#define GS_CH 128
__global__ __launch_bounds__(128) void graph_reduce_kernel(
        const unsigned short* __restrict__ h3, const int* __restrict__ batch,
        float* __restrict__ g, float* __restrict__ cnt, int N) {
    int o = threadIdx.x;
    int n0 = blockIdx.x * GS_CH;
    int n1 = min(n0 + GS_CH, N);
    if (o < 124) {
        float local = 0.0f;
        int cur_b = batch[n0];
        for (int n = n0; n < n1; ++n) {
            int b = batch[n];
            if (b != cur_b) {
                atomicAdd(&g[cur_b * 124 + o], local);
                local = 0.0f;
                cur_b = b;
            }
            local += bf2f(h3[(size_t)n * 124 + o]);
        }
        atomicAdd(&g[cur_b * 124 + o], local);
    } else if (o == 124) {
        float localc = 0.0f;
        int cur_b = batch[n0];
        for (int n = n0; n < n1; ++n) {
            int b = batch[n];
            if (b != cur_b) {
                atomicAdd(&cnt[cur_b], localc);
                localc = 0.0f;
                cur_b = b;
            }
            localc += 1.0f;
        }
        atomicAdd(&cnt[cur_b], localc);
    }
}

__global__ void head_kernel(const float* __restrict__ g, const float* __restrict__ cnt,
                            const float* __restrict__ fcw, const float* __restrict__ fcb,
                            float* __restrict__ out) {
    __shared__ float logits[32];
    __shared__ float red[2];
    int b = blockIdx.x;
    int o = threadIdx.x;
    float c = fmaxf(cnt[b], 1.0f);
    if (o < 30) {
        float a = fcb[o];
        for (int i = 0; i < 124; ++i)
            a = fmaf(g[b * 124 + i] / c, fcw[i * 30 + o], a);
        logits[o] = a;
    }
    __syncthreads();
    if (o == 0) {
        float m = -1e30f;
        for (int j = 0; j < 30; ++j) m = fmaxf(m, logits[j]);
        float s = 0.0f;
        for (int j = 0; j < 30; ++j) s += expf(logits[j] - m);
        red[0] = m;
        red[1] = logf(s);
    }
    __syncthreads();
    if (o < 30) out[b * 30 + o] = logits[o] - red[0] - red[1];
}

// ---------------------------------------------------------------------------
// per-layer driver (node-chunked so acc fits whatever ws_size allows)
// ---------------------------------------------------------------------------
template<int I, int O, int OP>
static void run_layer(const unsigned short* hb, const unsigned short* WT, const float* bias,
                      unsigned short* hout, unsigned short* accB,
                      const int4* rec, const int* off,
                      int N, size_t avail, hipStream_t stream) {
    constexpr int KP = ((26 * I + 31) / 32) * 32;
    size_t perNode = (size_t)KP * 2;
    size_t maxNodesS = avail / perNode;
    int maxNodes = (maxNodesS > (size_t)N) ? N : (int)maxNodesS;
    if (maxNodes < 64) maxNodes = 64;
    for (int nlo = 0; nlo < N; nlo += maxNodes) {
        int nhi = nlo + maxNodes;
        if (nhi > N) nhi = N;
        int cn = nhi - nlo;
        seg_accum_kernel<I, KP><<<2048, 256, 0, stream>>>(hb, rec, off, accB, nlo, nhi);
        contract_mfma_kernel<KP, O, OP><<<(cn + 63) / 64, 256, 0, stream>>>(
            accB, WT, bias, hout, nlo, nhi);
    }
}

extern "C" void kernel_launch(void* const* d_in, const int* in_sizes, int n_in,
                              void* d_out, int out_size, void* d_ws, size_t ws_size,
                              hipStream_t stream) {
    const float* x      = (const float*)d_in[0];
    const int*   ei     = (const int*)  d_in[1];
    const float* pseudo = (const float*)d_in[2];
    const int*   batch  = (const int*)  d_in[3];
    const float* W1 = (const float*)d_in[4];
    const float* r1 = (const float*)d_in[5];
    const float* b1 = (const float*)d_in[6];
    const float* W2 = (const float*)d_in[7];
    const float* r2 = (const float*)d_in[8];
    const float* b2 = (const float*)d_in[9];
    const float* W3 = (const float*)d_in[10];
    const float* r3 = (const float*)d_in[11];
    const float* b3 = (const float*)d_in[12];
    const float* fcw = (const float*)d_in[13];
    const float* fcb = (const float*)d_in[14];

    int N = in_sizes[0] / 8;
    int E = in_sizes[1] / 2;
    const int* srcp = ei;
    const int* dstp = ei + E;

    constexpr int KP1 = 224, KP2 = 832, KP3 = 1664;

    // workspace carve (all pieces 16B-multiple)
    char* p = (char*)d_ws;
    unsigned short* xb  = (unsigned short*)p; p += (size_t)N * 8 * 2;
    unsigned short* h1  = (unsigned short*)p; p += (size_t)N * 32 * 2;
    unsigned short* h2  = (unsigned short*)p; p += (size_t)N * 64 * 2;
    unsigned short* h3  = (unsigned short*)p; p += (size_t)N * 124 * 2;
    float* gbuf = (float*)p; p += 64 * 124 * 4;
    float* cntF = (float*)p; p += 256;
    int*   cntI = (int*)p;   p += ((size_t)N * 4 + 15) & ~15ULL;
    int*   off  = (int*)p;   p += ((size_t)N * 4 + 15) & ~15ULL;
    int*   bsum = (int*)p;   p += SCAN_B * 4;
    int4*  rec  = (int4*)p;  p += (size_t)E * 16;
    unsigned short* WT1 = (unsigned short*)p; p += (size_t)32  * KP1 * 2;
    unsigned short* WT2 = (unsigned short*)p; p += (size_t)64  * KP2 * 2;
    unsigned short* WT3 = (unsigned short*)p; p += (size_t)128 * KP3 * 2;
    unsigned short* accB = (unsigned short*)p;
    size_t used = (size_t)(p - (char*)d_ws);
    size_t avail = (ws_size > used) ? (ws_size - used) : 0;

    // zero: gbuf + cntF + cntI (contiguous)
    hipMemsetAsync(gbuf, 0, 64 * 124 * 4 + 256 + (((size_t)N * 4 + 15) & ~15ULL), stream);

    // CSR build
    int nb_scan = (N + SCAN_B - 1) / SCAN_B;
    csr_count_kernel<<<(E + 255) / 256, 256, 0, stream>>>(dstp, cntI, E);
    scan1_kernel<<<nb_scan, SCAN_B, 0, stream>>>(cntI, off, bsum, N);
    scan2_kernel<<<1, SCAN_B, 0, stream>>>(bsum, nb_scan);
    scan3_kernel<<<nb_scan, SCAN_B, 0, stream>>>(off, bsum, N);
    csr_fill_kernel<<<(E + 255) / 256, 256, 0, stream>>>(srcp, dstp, pseudo, off, rec, E);

    // conversions / weight prep
    to_bf16_kernel<<<(N * 8 + 255) / 256, 256, 0, stream>>>(x, xb, N * 8);
    build_wt_kernel<KP1, 8,  32,  32 ><<<(32  * KP1 + 255) / 256, 256, 0, stream>>>(W1, r1, WT1);
    build_wt_kernel<KP2, 32, 64,  64 ><<<(64  * KP2 + 255) / 256, 256, 0, stream>>>(W2, r2, WT2);
    build_wt_kernel<KP3, 64, 124, 128><<<(128 * KP3 + 255) / 256, 256, 0, stream>>>(W3, r3, WT3);

    run_layer<8,  32,  32 >(xb, WT1, b1, h1, accB, rec, off, N, avail, stream);
    run_layer<32, 64,  64 >(h1, WT2, b2, h2, accB, rec, off, N, avail, stream);
    run_layer<64, 124, 128>(h2, WT3, b3, h3, accB, rec, off, N, avail, stream);

    graph_reduce_kernel<<<(N + GS_CH - 1) / GS_CH, 128, 0, stream>>>(h3, batch, gbuf, cntF, N);
    head_kernel<<<64, 64, 0, stream>>>(gbuf, cntF, fcw, fcb, (float*)d_out);
}